// Round 5
// baseline (6156.544 us; speedup 1.0000x reference)
//
#include <hip/hip_runtime.h>

#define NN 50000
#define DD 128
#define EE 800000
#define THRV 0.3f

typedef unsigned short u16;

__device__ __forceinline__ float bf2f(u16 u){
    union { unsigned int i; float f; } v; v.i = ((unsigned int)u) << 16; return v.f;
}
__device__ __forceinline__ u16 f2bf(float f){
    unsigned int x = __float_as_uint(f);
    unsigned int r = (x + 0x7fffu + ((x >> 16) & 1u)) >> 16;
    return (u16)r;
}

// ---------------------------------------------------------------------------
// K0: zero the fp32 accumulator
// ---------------------------------------------------------------------------
__global__ __launch_bounds__(256)
void k_zero(float* p, int n)
{
    int i = blockIdx.x * 256 + threadIdx.x;
    if (i < n) p[i] = 0.0f;
}

// ---------------------------------------------------------------------------
// K1: boundary MLP  b = sigmoid(relu(relu(x@W1+b1)@W2+b2)@W3+b3)   [2,N]
// All fp32 (the downstream >0.3 comparisons are discrete decisions).
// ---------------------------------------------------------------------------
__global__ __launch_bounds__(256)
void k_boundary(const float* x,
                const float* bdW1, const float* bdb1,
                const float* bdW2, const float* bdb2,
                const float* bdW3, const float* bdb3,
                float* bws)
{
    __shared__ __align__(16) char smem[58372];
    float* Xs  = (float*)(smem);           // [64][129] fp32 X tile
    float* H1  = (float*)(smem + 33024);   // [64][65]
    float* W2s = (float*)(smem + 49664);   // [64][32]
    float* W3s = (float*)(smem + 57856);   // [32]
    float* b2s = (float*)(smem + 57984);   // [32]
    float* b3s = (float*)(smem + 58112);   // [1]
    float* b1s = (float*)(smem + 58116);   // [64]
    float* H2s = (float*)(smem);           // [64][33], aliases Xs (dead after ph1)

    const int t  = threadIdx.x;
    const int et = blockIdx.y;
    const int R0 = blockIdx.x * 64;

    {   // stage X tile (zero-fill OOB rows)
        int r = t >> 2, c0 = (t & 3) * 32;
        int row = R0 + r;
        const float* xr = x + ((long)et * NN + row) * DD + c0;
        for (int j = 0; j < 32; j++)
            Xs[r * 129 + c0 + j] = (row < NN) ? xr[j] : 0.0f;
    }
    if (t < 64) b1s[t] = bdb1[et * 64 + t];
    __syncthreads();

    // phase 1: H1[64][64] = relu(X @ W1 + b1); 16x16 threads, 4 rows x 4 cols
    const int tc = t & 15, tr = t >> 4;
    {
        const float* W1g = bdW1 + et * 8192;     // [128][64], via L2
        float acc[4][4];
        for (int m = 0; m < 4; m++)
            for (int j = 0; j < 4; j++) acc[m][j] = 0.0f;
        for (int k = 0; k < 128; k++){
            float xv[4], wv[4];
            #pragma unroll
            for (int m = 0; m < 4; m++) xv[m] = Xs[(tr + 16 * m) * 129 + k];
            #pragma unroll
            for (int j = 0; j < 4; j++) wv[j] = W1g[k * 64 + tc * 4 + j];
            #pragma unroll
            for (int m = 0; m < 4; m++)
                #pragma unroll
                for (int j = 0; j < 4; j++)
                    acc[m][j] += xv[m] * wv[j];
        }
        for (int m = 0; m < 4; m++)
            for (int j = 0; j < 4; j++){
                int row = tr + 16 * m, col = tc * 4 + j;
                float v = acc[m][j] + b1s[col];
                H1[row * 65 + col] = v > 0.0f ? v : 0.0f;
            }
    }
    // stage W2/W3/b2/b3
    for (int idx = t; idx < 2048; idx += 256)
        W2s[idx] = bdW2[et * 2048 + idx];         // [64][32]
    if (t < 32){
        W3s[t] = bdW3[et * 32 + t];
        b2s[t] = bdb2[et * 32 + t];
    }
    if (t == 0) b3s[0] = bdb3[et];
    __syncthreads();

    // phase 2: H2[64][32] = relu(H1 @ W2 + b2); 32 cols x 8 thread-rows
    {
        int c2 = t & 31, r2 = t >> 5;
        float a2[8];
        for (int i = 0; i < 8; i++) a2[i] = b2s[c2];
        for (int k = 0; k < 64; k++){
            float wv = W2s[k * 32 + c2];
            #pragma unroll
            for (int i = 0; i < 8; i++)
                a2[i] += H1[(r2 + 8 * i) * 65 + k] * wv;
        }
        for (int i = 0; i < 8; i++)
            H2s[(r2 + 8 * i) * 33 + c2] = a2[i] > 0.0f ? a2[i] : 0.0f;
    }
    __syncthreads();

    // phase 3: dot-32 + sigmoid
    if (t < 64){
        float z = b3s[0];
        for (int j = 0; j < 32; j++)
            z += H2s[t * 33 + j] * W3s[j];
        float b = 1.0f / (1.0f + expf(-z));
        int row = R0 + t;
        if (row < NN) bws[et * NN + row] = b;
    }
}

// ---------------------------------------------------------------------------
// K2: edge transform  t = relu(x@W1+b1)@W2+b2  -> bf16 [2,N,128] in workspace
// ---------------------------------------------------------------------------
__global__ __launch_bounds__(256)
void k_edgetrans(const float* x,
                 const float* etW1, const float* etb1,
                 const float* etW2, const float* etb2,
                 u16* tws)
{
    __shared__ __align__(16) char smem[34048];
    float* Xs  = (float*)(smem);           // [64][129] fp32 (X, then H)
    float* b1s = (float*)(smem + 33024);   // [128]
    float* b2s = (float*)(smem + 33536);   // [128]

    const int t  = threadIdx.x;
    const int et = blockIdx.y;
    const int R0 = blockIdx.x * 64;

    {   // stage X
        int r = t >> 2, c0 = (t & 3) * 32;
        int row = R0 + r;
        const float* xr = x + ((long)et * NN + row) * DD + c0;
        for (int j = 0; j < 32; j++)
            Xs[r * 129 + c0 + j] = (row < NN) ? xr[j] : 0.0f;
    }
    if (t < 128) b1s[t] = etb1[et * 128 + t];
    else         b2s[t - 128] = etb2[et * 128 + (t - 128)];
    __syncthreads();

    const int tc = t & 15, tr = t >> 4;   // 16x16 threads; 4 rows x 8 cols each
    const float* W1g = etW1 + et * 16384;  // [128][128], via L2
    float acc[4][8];
    for (int m = 0; m < 4; m++)
        for (int j = 0; j < 8; j++) acc[m][j] = 0.0f;
    for (int k = 0; k < 128; k++){
        float xv[4], wv[8];
        #pragma unroll
        for (int m = 0; m < 4; m++) xv[m] = Xs[(tr + 16 * m) * 129 + k];
        #pragma unroll
        for (int j = 0; j < 8; j++) wv[j] = W1g[k * 128 + tc * 8 + j];
        #pragma unroll
        for (int m = 0; m < 4; m++)
            #pragma unroll
            for (int j = 0; j < 8; j++)
                acc[m][j] += xv[m] * wv[j];
    }
    __syncthreads();   // all reads of Xs done before overwrite

    // H = relu(acc + b1) into Xs
    for (int m = 0; m < 4; m++)
        for (int j = 0; j < 8; j++){
            int row = tr + 16 * m, col = tc * 8 + j;
            float v = acc[m][j] + b1s[col];
            Xs[row * 129 + col] = v > 0.0f ? v : 0.0f;
        }
    __syncthreads();

    const float* W2g = etW2 + et * 16384;
    float acc2[4][8];
    for (int m = 0; m < 4; m++)
        for (int j = 0; j < 8; j++) acc2[m][j] = 0.0f;
    for (int k = 0; k < 128; k++){
        float xv[4], wv[8];
        #pragma unroll
        for (int m = 0; m < 4; m++) xv[m] = Xs[(tr + 16 * m) * 129 + k];
        #pragma unroll
        for (int j = 0; j < 8; j++) wv[j] = W2g[k * 128 + tc * 8 + j];
        #pragma unroll
        for (int m = 0; m < 4; m++)
            #pragma unroll
            for (int j = 0; j < 8; j++)
                acc2[m][j] += xv[m] * wv[j];
    }
    for (int m = 0; m < 4; m++){
        int row = R0 + tr + 16 * m;
        if (row < NN){
            u16* op = tws + ((long)et * NN + row) * DD + tc * 8;
            for (int j = 0; j < 8; j++)
                op[j] = f2bf(acc2[m][j] + b2s[tc * 8 + j]);
        }
    }
}

// ---------------------------------------------------------------------------
// K3: per-edge coefficient c = ea * (2x-enhanced) sigmoid MLP(sb, db)
// ---------------------------------------------------------------------------
__global__ __launch_bounds__(256)
void k_coef(const int* ei, const float* ea,
            const float* bwW1, const float* bwb1,
            const float* bwW2, const float* bwb2,
            const float* bwW3, const float* bwb3,
            const float* bws, float* cws)
{
    __shared__ float W1s[64];
    __shared__ float b1sh[32];
    __shared__ float W2s[512];
    __shared__ float b2sh[16];
    __shared__ float W3s[16];
    __shared__ float b3sh[1];
    const int t  = threadIdx.x;
    const int et = blockIdx.y;

    if (t < 64)        W1s[t]        = bwW1[et * 64 + t];
    else if (t < 96)   b1sh[t - 64]  = bwb1[et * 32 + (t - 64)];
    else if (t < 112)  b2sh[t - 96]  = bwb2[et * 16 + (t - 96)];
    else if (t < 128)  W3s[t - 112]  = bwW3[et * 16 + (t - 112)];
    else if (t == 128) b3sh[0]       = bwb3[et];
    for (int idx = t; idx < 512; idx += 256)
        W2s[idx] = bwW2[et * 512 + idx];
    __syncthreads();

    int e = blockIdx.x * 256 + t;
    if (e >= EE) return;
    int src = ei[(et * 2 + 0) * EE + e];
    int dst = ei[(et * 2 + 1) * EE + e];
    float sb = bws[et * NN + src];
    float db = bws[(1 - et) * NN + dst];

    float h1[32];
    #pragma unroll
    for (int j = 0; j < 32; j++){
        float v = sb * W1s[j] + db * W1s[32 + j] + b1sh[j];
        h1[j] = v > 0.0f ? v : 0.0f;
    }
    float h2[16];
    #pragma unroll
    for (int k = 0; k < 16; k++) h2[k] = b2sh[k];
    #pragma unroll
    for (int j = 0; j < 32; j++){
        float hv = h1[j];
        #pragma unroll
        for (int k = 0; k < 16; k++)
            h2[k] += hv * W2s[j * 16 + k];
    }
    float z = b3sh[0];
    #pragma unroll
    for (int k = 0; k < 16; k++){
        float hv = h2[k] > 0.0f ? h2[k] : 0.0f;
        z += hv * W3s[k];
    }
    float wv = 1.0f / (1.0f + expf(-z));
    if (sb > THRV || db > THRV) wv *= 2.0f;
    cws[et * EE + e] = ea[et * EE + e] * wv;
}

// ---------------------------------------------------------------------------
// K4: scatter  agg[1-et][dst] += t[et][src] * c   (fp32 atomics)
// 16 lanes/edge x 8 dims each (dword loads of 2 bf16)
// ---------------------------------------------------------------------------
__global__ __launch_bounds__(256)
void k_scatter(const int* ei, const float* cws,
               const u16* tws, float* agg)
{
    const int t  = threadIdx.x;
    const int et = blockIdx.y;
    int e   = blockIdx.x * 16 + (t >> 4);
    int sub = t & 15;
    int src = ei[(et * 2 + 0) * EE + e];
    int dst = ei[(et * 2 + 1) * EE + e];
    float c = cws[et * EE + e];
    const unsigned int* tp =
        (const unsigned int*)(tws + ((long)et * NN + src) * DD + sub * 8);
    float* op = agg + ((long)(1 - et) * NN + dst) * DD + sub * 8;
    #pragma unroll
    for (int i = 0; i < 4; i++){
        unsigned int pv = tp[i];
        atomicAdd(op + 2 * i,     bf2f((u16)(pv & 0xffffu)) * c);
        atomicAdd(op + 2 * i + 1, bf2f((u16)(pv >> 16)) * c);
    }
}

// ---------------------------------------------------------------------------
// K5: U = agg + x; z = U@nuW + nub; LayerNorm; relu -> out fp32
// ---------------------------------------------------------------------------
__global__ __launch_bounds__(256)
void k_final(const float* agg, const float* x,
             const float* nuW, const float* nub,
             const float* lng, const float* lnb,
             float* out)
{
    __shared__ __align__(16) char smem[34560];
    float* Us   = (float*)(smem);           // [64][129] fp32 U tile; z aliases
    float* nubs = (float*)(smem + 33024);   // [128]
    float* lngs = (float*)(smem + 33536);   // [128]
    float* lnbs = (float*)(smem + 34048);   // [128]

    const int t  = threadIdx.x;
    const int et = blockIdx.y;
    const int R0 = blockIdx.x * 64;

    {   // stage U = agg + x
        int r = t >> 2, c0 = (t & 3) * 32;
        int row = R0 + r;
        const float* xr = x   + ((long)et * NN + row) * DD + c0;
        const float* ar = agg + ((long)et * NN + row) * DD + c0;
        for (int j = 0; j < 32; j++)
            Us[r * 129 + c0 + j] = (row < NN) ? (ar[j] + xr[j]) : 0.0f;
    }
    if (t < 128) nubs[t] = nub[et * 128 + t];
    else {
        lngs[t - 128] = lng[et * 128 + (t - 128)];
        lnbs[t - 128] = lnb[et * 128 + (t - 128)];
    }
    __syncthreads();

    const int tc = t & 15, tr = t >> 4;
    const float* Wg = nuW + et * 16384;    // [128][128], via L2
    float acc[4][8];
    for (int m = 0; m < 4; m++)
        for (int j = 0; j < 8; j++) acc[m][j] = 0.0f;
    for (int k = 0; k < 128; k++){
        float xv[4], wv[8];
        #pragma unroll
        for (int m = 0; m < 4; m++) xv[m] = Us[(tr + 16 * m) * 129 + k];
        #pragma unroll
        for (int j = 0; j < 8; j++) wv[j] = Wg[k * 128 + tc * 8 + j];
        #pragma unroll
        for (int m = 0; m < 4; m++)
            #pragma unroll
            for (int j = 0; j < 8; j++)
                acc[m][j] += xv[m] * wv[j];
    }
    __syncthreads();   // all reads of Us done before overwrite with z

    for (int m = 0; m < 4; m++)
        for (int j = 0; j < 8; j++){
            int row = tr + 16 * m, col = tc * 8 + j;
            Us[row * 129 + col] = acc[m][j] + nubs[col];   // z
        }
    __syncthreads();

    // LayerNorm + relu + fp32 store; 4 threads per row
    {
        int row = t >> 2, sub = t & 3;
        const float* zr = Us + row * 129 + sub * 32;
        float s = 0.0f, ss = 0.0f;
        for (int j = 0; j < 32; j++){ float v = zr[j]; s += v; ss += v * v; }
        s  += __shfl_xor(s, 1);  s  += __shfl_xor(s, 2);
        ss += __shfl_xor(ss, 1); ss += __shfl_xor(ss, 2);
        float mean = s * (1.0f / 128.0f);
        float var  = ss * (1.0f / 128.0f) - mean * mean;
        float rstd = rsqrtf(var + 1e-5f);
        int grow = R0 + row;
        if (grow < NN){
            float* op = out + ((long)et * NN + grow) * DD + sub * 32;
            for (int j = 0; j < 32; j++){
                int col = sub * 32 + j;
                float zn = (zr[j] - mean) * rstd;
                float o  = zn * lngs[col] + lnbs[col];
                op[j] = o > 0.0f ? o : 0.0f;
            }
        }
    }
}

// ---------------------------------------------------------------------------
extern "C" void kernel_launch(void* const* d_in, const int* in_sizes, int n_in,
                              void* d_out, int out_size, void* d_ws, size_t ws_size,
                              hipStream_t stream)
{
    const float* x    = (const float*)d_in[0];
    const int*   ei   = (const int*)d_in[1];
    const float* ea   = (const float*)d_in[2];
    const float* bdW1 = (const float*)d_in[3];
    const float* bdb1 = (const float*)d_in[4];
    const float* bdW2 = (const float*)d_in[5];
    const float* bdb2 = (const float*)d_in[6];
    const float* bdW3 = (const float*)d_in[7];
    const float* bdb3 = (const float*)d_in[8];
    const float* etW1 = (const float*)d_in[9];
    const float* etb1 = (const float*)d_in[10];
    const float* etW2 = (const float*)d_in[11];
    const float* etb2 = (const float*)d_in[12];
    const float* bwW1 = (const float*)d_in[13];
    const float* bwb1 = (const float*)d_in[14];
    const float* bwW2 = (const float*)d_in[15];
    const float* bwb2 = (const float*)d_in[16];
    const float* bwW3 = (const float*)d_in[17];
    const float* bwb3 = (const float*)d_in[18];
    const float* nuW  = (const float*)d_in[19];
    const float* nub  = (const float*)d_in[20];
    const float* lng  = (const float*)d_in[21];
    const float* lnb  = (const float*)d_in[22];

    // workspace layout (bytes):
    //   agg  [2*N*128] f32 : 51,200,000
    //   tws  [2*N*128] bf16: 25,600,000
    //   bws  [2*N]     f32 :    400,000
    //   cws  [2*E]     f32 :  6,400,000   total 83.6 MB
    char* wsb  = (char*)d_ws;
    float* agg = (float*)wsb;
    u16*   tws = (u16*)(wsb + (long)2 * NN * DD * 4);
    float* bws = (float*)(wsb + (long)2 * NN * DD * 4 + (long)2 * NN * DD * 2);
    float* cws = (float*)((char*)bws + (long)2 * NN * 4);

    dim3 blk(256);
    const int aggN = 2 * NN * DD;
    k_zero<<<dim3((aggN + 255) / 256), blk, 0, stream>>>(agg, aggN);

    dim3 g1((NN + 63) / 64, 2);
    k_boundary<<<g1, blk, 0, stream>>>(x, bdW1, bdb1, bdW2, bdb2, bdW3, bdb3, bws);
    k_edgetrans<<<g1, blk, 0, stream>>>(x, etW1, etb1, etW2, etb2, tws);
    k_coef<<<dim3((EE + 255) / 256, 2), blk, 0, stream>>>(ei, ea, bwW1, bwb1, bwW2, bwb2,
                                                          bwW3, bwb3, bws, cws);
    k_scatter<<<dim3(EE / 16, 2), blk, 0, stream>>>(ei, cws, tws, agg);
    k_final<<<g1, blk, 0, stream>>>(agg, x, nuW, nub, lng, lnb, (float*)d_out);
}

// Round 6
// 1317.945 us; speedup vs baseline: 4.6713x; 4.6713x over previous
//
#include <hip/hip_runtime.h>

#define NN 50000
#define DD 128
#define EE 800000
#define THRV 0.3f

typedef unsigned short u16;

__device__ __forceinline__ float bf2f(u16 u){
    union { unsigned int i; float f; } v; v.i = ((unsigned int)u) << 16; return v.f;
}
__device__ __forceinline__ u16 f2bf(float f){
    unsigned int x = __float_as_uint(f);
    unsigned int r = (x + 0x7fffu + ((x >> 16) & 1u)) >> 16;
    return (u16)r;
}

// ---------------------------------------------------------------------------
// K0: zero the per-(et,dst) degree counters
// ---------------------------------------------------------------------------
__global__ __launch_bounds__(256)
void k_zero(int* p, int n)
{
    int i = blockIdx.x * 256 + threadIdx.x;
    if (i < n) p[i] = 0;
}

// ---------------------------------------------------------------------------
// K1: boundary MLP  b = sigmoid(relu(relu(x@W1+b1)@W2+b2)@W3+b3)   [2,N]
// All fp32 (the downstream >0.3 comparisons are discrete decisions).
// ---------------------------------------------------------------------------
__global__ __launch_bounds__(256)
void k_boundary(const float* x,
                const float* bdW1, const float* bdb1,
                const float* bdW2, const float* bdb2,
                const float* bdW3, const float* bdb3,
                float* bws)
{
    __shared__ __align__(16) char smem[58372];
    float* Xs  = (float*)(smem);           // [64][129] fp32 X tile
    float* H1  = (float*)(smem + 33024);   // [64][65]
    float* W2s = (float*)(smem + 49664);   // [64][32]
    float* W3s = (float*)(smem + 57856);   // [32]
    float* b2s = (float*)(smem + 57984);   // [32]
    float* b3s = (float*)(smem + 58112);   // [1]
    float* b1s = (float*)(smem + 58116);   // [64]
    float* H2s = (float*)(smem);           // [64][33], aliases Xs (dead after ph1)

    const int t  = threadIdx.x;
    const int et = blockIdx.y;
    const int R0 = blockIdx.x * 64;

    {   // stage X tile (zero-fill OOB rows)
        int r = t >> 2, c0 = (t & 3) * 32;
        int row = R0 + r;
        const float* xr = x + ((long)et * NN + row) * DD + c0;
        for (int j = 0; j < 32; j++)
            Xs[r * 129 + c0 + j] = (row < NN) ? xr[j] : 0.0f;
    }
    if (t < 64) b1s[t] = bdb1[et * 64 + t];
    __syncthreads();

    // phase 1: H1[64][64] = relu(X @ W1 + b1); 16x16 threads, 4 rows x 4 cols
    const int tc = t & 15, tr = t >> 4;
    {
        const float* W1g = bdW1 + et * 8192;     // [128][64], via L2
        float acc[4][4];
        for (int m = 0; m < 4; m++)
            for (int j = 0; j < 4; j++) acc[m][j] = 0.0f;
        for (int k = 0; k < 128; k++){
            float xv[4], wv[4];
            #pragma unroll
            for (int m = 0; m < 4; m++) xv[m] = Xs[(tr + 16 * m) * 129 + k];
            #pragma unroll
            for (int j = 0; j < 4; j++) wv[j] = W1g[k * 64 + tc * 4 + j];
            #pragma unroll
            for (int m = 0; m < 4; m++)
                #pragma unroll
                for (int j = 0; j < 4; j++)
                    acc[m][j] += xv[m] * wv[j];
        }
        for (int m = 0; m < 4; m++)
            for (int j = 0; j < 4; j++){
                int row = tr + 16 * m, col = tc * 4 + j;
                float v = acc[m][j] + b1s[col];
                H1[row * 65 + col] = v > 0.0f ? v : 0.0f;
            }
    }
    // stage W2/W3/b2/b3
    for (int idx = t; idx < 2048; idx += 256)
        W2s[idx] = bdW2[et * 2048 + idx];         // [64][32]
    if (t < 32){
        W3s[t] = bdW3[et * 32 + t];
        b2s[t] = bdb2[et * 32 + t];
    }
    if (t == 0) b3s[0] = bdb3[et];
    __syncthreads();

    // phase 2: H2[64][32] = relu(H1 @ W2 + b2); 32 cols x 8 thread-rows
    {
        int c2 = t & 31, r2 = t >> 5;
        float a2[8];
        for (int i = 0; i < 8; i++) a2[i] = b2s[c2];
        for (int k = 0; k < 64; k++){
            float wv = W2s[k * 32 + c2];
            #pragma unroll
            for (int i = 0; i < 8; i++)
                a2[i] += H1[(r2 + 8 * i) * 65 + k] * wv;
        }
        for (int i = 0; i < 8; i++)
            H2s[(r2 + 8 * i) * 33 + c2] = a2[i] > 0.0f ? a2[i] : 0.0f;
    }
    __syncthreads();

    // phase 3: dot-32 + sigmoid
    if (t < 64){
        float z = b3s[0];
        for (int j = 0; j < 32; j++)
            z += H2s[t * 33 + j] * W3s[j];
        float b = 1.0f / (1.0f + expf(-z));
        int row = R0 + t;
        if (row < NN) bws[et * NN + row] = b;
    }
}

// ---------------------------------------------------------------------------
// K2: edge transform  t = relu(x@W1+b1)@W2+b2  -> bf16 [2,N,128] in workspace
// ---------------------------------------------------------------------------
__global__ __launch_bounds__(256)
void k_edgetrans(const float* x,
                 const float* etW1, const float* etb1,
                 const float* etW2, const float* etb2,
                 u16* tws)
{
    __shared__ __align__(16) char smem[34048];
    float* Xs  = (float*)(smem);           // [64][129] fp32 (X, then H)
    float* b1s = (float*)(smem + 33024);   // [128]
    float* b2s = (float*)(smem + 33536);   // [128]

    const int t  = threadIdx.x;
    const int et = blockIdx.y;
    const int R0 = blockIdx.x * 64;

    {   // stage X
        int r = t >> 2, c0 = (t & 3) * 32;
        int row = R0 + r;
        const float* xr = x + ((long)et * NN + row) * DD + c0;
        for (int j = 0; j < 32; j++)
            Xs[r * 129 + c0 + j] = (row < NN) ? xr[j] : 0.0f;
    }
    if (t < 128) b1s[t] = etb1[et * 128 + t];
    else         b2s[t - 128] = etb2[et * 128 + (t - 128)];
    __syncthreads();

    const int tc = t & 15, tr = t >> 4;   // 16x16 threads; 4 rows x 8 cols each
    const float* W1g = etW1 + et * 16384;  // [128][128], via L2
    float acc[4][8];
    for (int m = 0; m < 4; m++)
        for (int j = 0; j < 8; j++) acc[m][j] = 0.0f;
    for (int k = 0; k < 128; k++){
        float xv[4], wv[8];
        #pragma unroll
        for (int m = 0; m < 4; m++) xv[m] = Xs[(tr + 16 * m) * 129 + k];
        #pragma unroll
        for (int j = 0; j < 8; j++) wv[j] = W1g[k * 128 + tc * 8 + j];
        #pragma unroll
        for (int m = 0; m < 4; m++)
            #pragma unroll
            for (int j = 0; j < 8; j++)
                acc[m][j] += xv[m] * wv[j];
    }
    __syncthreads();   // all reads of Xs done before overwrite

    // H = relu(acc + b1) into Xs
    for (int m = 0; m < 4; m++)
        for (int j = 0; j < 8; j++){
            int row = tr + 16 * m, col = tc * 8 + j;
            float v = acc[m][j] + b1s[col];
            Xs[row * 129 + col] = v > 0.0f ? v : 0.0f;
        }
    __syncthreads();

    const float* W2g = etW2 + et * 16384;
    float acc2[4][8];
    for (int m = 0; m < 4; m++)
        for (int j = 0; j < 8; j++) acc2[m][j] = 0.0f;
    for (int k = 0; k < 128; k++){
        float xv[4], wv[8];
        #pragma unroll
        for (int m = 0; m < 4; m++) xv[m] = Xs[(tr + 16 * m) * 129 + k];
        #pragma unroll
        for (int j = 0; j < 8; j++) wv[j] = W2g[k * 128 + tc * 8 + j];
        #pragma unroll
        for (int m = 0; m < 4; m++)
            #pragma unroll
            for (int j = 0; j < 8; j++)
                acc2[m][j] += xv[m] * wv[j];
    }
    for (int m = 0; m < 4; m++){
        int row = R0 + tr + 16 * m;
        if (row < NN){
            u16* op = tws + ((long)et * NN + row) * DD + tc * 8;
            for (int j = 0; j < 8; j++)
                op[j] = f2bf(acc2[m][j] + b2s[tc * 8 + j]);
        }
    }
}

// ---------------------------------------------------------------------------
// K3: histogram of edges by dst:  deg[et][dst]++
// ---------------------------------------------------------------------------
__global__ __launch_bounds__(256)
void k_hist(const int* ei, int* deg)
{
    const int et = blockIdx.y;
    int e = blockIdx.x * 256 + threadIdx.x;
    int dst = ei[(et * 2 + 1) * EE + e];
    atomicAdd(&deg[et * NN + dst], 1);
}

// ---------------------------------------------------------------------------
// K4: exclusive scan of deg -> rowptr (and cursor copy); 1 block per et
// ---------------------------------------------------------------------------
__global__ __launch_bounds__(256)
void k_scan(const int* deg, int* rowptr, int* cursor)
{
    __shared__ int buf[256];
    __shared__ int carry;
    const int et = blockIdx.y;
    const int t  = threadIdx.x;
    if (t == 0) carry = 0;
    __syncthreads();
    for (int base = 0; base < NN; base += 256){
        int i = base + t;
        int v = (i < NN) ? deg[et * NN + i] : 0;
        buf[t] = v;
        __syncthreads();
        #pragma unroll
        for (int off = 1; off < 256; off <<= 1){
            int xv = (t >= off) ? buf[t - off] : 0;
            __syncthreads();
            buf[t] += xv;
            __syncthreads();
        }
        int incl = buf[t];
        int excl = incl - v + carry;
        if (i < NN){
            rowptr[et * NN + i] = excl;
            cursor[et * NN + i] = excl;
        }
        __syncthreads();
        if (t == 255) carry = excl + v;
        __syncthreads();
    }
}

// ---------------------------------------------------------------------------
// K5: per-edge coefficient MLP + CSR placement (fused old k_coef + fill)
//     esrc[et][pos] = src, ecoef[et][pos] = ea * (2x-enhanced) sigmoid MLP
// ---------------------------------------------------------------------------
__global__ __launch_bounds__(256)
void k_place(const int* ei, const float* ea,
             const float* bwW1, const float* bwb1,
             const float* bwW2, const float* bwb2,
             const float* bwW3, const float* bwb3,
             const float* bws, int* cursor,
             int* esrc, float* ecoef)
{
    __shared__ float W1s[64];
    __shared__ float b1sh[32];
    __shared__ float W2s[512];
    __shared__ float b2sh[16];
    __shared__ float W3s[16];
    __shared__ float b3sh[1];
    const int t  = threadIdx.x;
    const int et = blockIdx.y;

    if (t < 64)        W1s[t]        = bwW1[et * 64 + t];
    else if (t < 96)   b1sh[t - 64]  = bwb1[et * 32 + (t - 64)];
    else if (t < 112)  b2sh[t - 96]  = bwb2[et * 16 + (t - 96)];
    else if (t < 128)  W3s[t - 112]  = bwW3[et * 16 + (t - 112)];
    else if (t == 128) b3sh[0]       = bwb3[et];
    for (int idx = t; idx < 512; idx += 256)
        W2s[idx] = bwW2[et * 512 + idx];
    __syncthreads();

    int e   = blockIdx.x * 256 + t;
    int src = ei[(et * 2 + 0) * EE + e];
    int dst = ei[(et * 2 + 1) * EE + e];
    float sb = bws[et * NN + src];
    float db = bws[(1 - et) * NN + dst];

    float h1[32];
    #pragma unroll
    for (int j = 0; j < 32; j++){
        float v = sb * W1s[j] + db * W1s[32 + j] + b1sh[j];
        h1[j] = v > 0.0f ? v : 0.0f;
    }
    float h2[16];
    #pragma unroll
    for (int k = 0; k < 16; k++) h2[k] = b2sh[k];
    #pragma unroll
    for (int j = 0; j < 32; j++){
        float hv = h1[j];
        #pragma unroll
        for (int k = 0; k < 16; k++)
            h2[k] += hv * W2s[j * 16 + k];
    }
    float z = b3sh[0];
    #pragma unroll
    for (int k = 0; k < 16; k++){
        float hv = h2[k] > 0.0f ? h2[k] : 0.0f;
        z += hv * W3s[k];
    }
    float wv = 1.0f / (1.0f + expf(-z));
    if (sb > THRV || db > THRV) wv *= 2.0f;
    float c = ea[et * EE + e] * wv;

    int pos = atomicAdd(&cursor[et * NN + dst], 1);
    esrc [(long)et * EE + pos] = src;
    ecoef[(long)et * EE + pos] = c;
}

// ---------------------------------------------------------------------------
// K6: CSR gather — one wave per dst node, 2 dims per lane, fp32 registers.
//     agg[1-et][n][:] = sum_k t[et][esrc[k]][:] * ecoef[k]
//     Writes every element -> no zero-init of agg needed, no atomics.
// ---------------------------------------------------------------------------
__global__ __launch_bounds__(256)
void k_gather(const int* rowptr, const int* deg,
              const int* esrc, const float* ecoef,
              const u16* tws, float* agg)
{
    const int et   = blockIdx.y;
    const int w    = threadIdx.x >> 6;
    const int lane = threadIdx.x & 63;
    const int n    = blockIdx.x * 4 + w;          // 12500*4 = 50000 exactly

    int start = rowptr[et * NN + n];
    int cnt   = deg[et * NN + n];
    const int*   es = esrc  + (long)et * EE + start;
    const float* ec = ecoef + (long)et * EE + start;

    float a0 = 0.0f, a1 = 0.0f;
    for (int k = 0; k < cnt; k++){
        int   src = es[k];
        float c   = ec[k];
        unsigned int pv = *(const unsigned int*)(tws + ((long)et * NN + src) * DD + lane * 2);
        a0 += bf2f((u16)(pv & 0xffffu)) * c;
        a1 += bf2f((u16)(pv >> 16)) * c;
    }
    float* op = agg + ((long)(1 - et) * NN + n) * DD + lane * 2;
    op[0] = a0;
    op[1] = a1;
}

// ---------------------------------------------------------------------------
// K7: U = agg + x; z = U@nuW + nub; LayerNorm; relu -> out fp32
// ---------------------------------------------------------------------------
__global__ __launch_bounds__(256)
void k_final(const float* agg, const float* x,
             const float* nuW, const float* nub,
             const float* lng, const float* lnb,
             float* out)
{
    __shared__ __align__(16) char smem[34560];
    float* Us   = (float*)(smem);           // [64][129] fp32 U tile; z aliases
    float* nubs = (float*)(smem + 33024);   // [128]
    float* lngs = (float*)(smem + 33536);   // [128]
    float* lnbs = (float*)(smem + 34048);   // [128]

    const int t  = threadIdx.x;
    const int et = blockIdx.y;
    const int R0 = blockIdx.x * 64;

    {   // stage U = agg + x
        int r = t >> 2, c0 = (t & 3) * 32;
        int row = R0 + r;
        const float* xr = x   + ((long)et * NN + row) * DD + c0;
        const float* ar = agg + ((long)et * NN + row) * DD + c0;
        for (int j = 0; j < 32; j++)
            Us[r * 129 + c0 + j] = (row < NN) ? (ar[j] + xr[j]) : 0.0f;
    }
    if (t < 128) nubs[t] = nub[et * 128 + t];
    else {
        lngs[t - 128] = lng[et * 128 + (t - 128)];
        lnbs[t - 128] = lnb[et * 128 + (t - 128)];
    }
    __syncthreads();

    const int tc = t & 15, tr = t >> 4;
    const float* Wg = nuW + et * 16384;    // [128][128], via L2
    float acc[4][8];
    for (int m = 0; m < 4; m++)
        for (int j = 0; j < 8; j++) acc[m][j] = 0.0f;
    for (int k = 0; k < 128; k++){
        float xv[4], wv[8];
        #pragma unroll
        for (int m = 0; m < 4; m++) xv[m] = Us[(tr + 16 * m) * 129 + k];
        #pragma unroll
        for (int j = 0; j < 8; j++) wv[j] = Wg[k * 128 + tc * 8 + j];
        #pragma unroll
        for (int m = 0; m < 4; m++)
            #pragma unroll
            for (int j = 0; j < 8; j++)
                acc[m][j] += xv[m] * wv[j];
    }
    __syncthreads();   // all reads of Us done before overwrite with z

    for (int m = 0; m < 4; m++)
        for (int j = 0; j < 8; j++){
            int row = tr + 16 * m, col = tc * 8 + j;
            Us[row * 129 + col] = acc[m][j] + nubs[col];   // z
        }
    __syncthreads();

    // LayerNorm + relu + fp32 store; 4 threads per row
    {
        int row = t >> 2, sub = t & 3;
        const float* zr = Us + row * 129 + sub * 32;
        float s = 0.0f, ss = 0.0f;
        for (int j = 0; j < 32; j++){ float v = zr[j]; s += v; ss += v * v; }
        s  += __shfl_xor(s, 1);  s  += __shfl_xor(s, 2);
        ss += __shfl_xor(ss, 1); ss += __shfl_xor(ss, 2);
        float mean = s * (1.0f / 128.0f);
        float var  = ss * (1.0f / 128.0f) - mean * mean;
        float rstd = rsqrtf(var + 1e-5f);
        int grow = R0 + row;
        if (grow < NN){
            float* op = out + ((long)et * NN + grow) * DD + sub * 32;
            for (int j = 0; j < 32; j++){
                int col = sub * 32 + j;
                float zn = (zr[j] - mean) * rstd;
                float o  = zn * lngs[col] + lnbs[col];
                op[j] = o > 0.0f ? o : 0.0f;
            }
        }
    }
}

// ---------------------------------------------------------------------------
extern "C" void kernel_launch(void* const* d_in, const int* in_sizes, int n_in,
                              void* d_out, int out_size, void* d_ws, size_t ws_size,
                              hipStream_t stream)
{
    const float* x    = (const float*)d_in[0];
    const int*   ei   = (const int*)d_in[1];
    const float* ea   = (const float*)d_in[2];
    const float* bdW1 = (const float*)d_in[3];
    const float* bdb1 = (const float*)d_in[4];
    const float* bdW2 = (const float*)d_in[5];
    const float* bdb2 = (const float*)d_in[6];
    const float* bdW3 = (const float*)d_in[7];
    const float* bdb3 = (const float*)d_in[8];
    const float* etW1 = (const float*)d_in[9];
    const float* etb1 = (const float*)d_in[10];
    const float* etW2 = (const float*)d_in[11];
    const float* etb2 = (const float*)d_in[12];
    const float* bwW1 = (const float*)d_in[13];
    const float* bwb1 = (const float*)d_in[14];
    const float* bwW2 = (const float*)d_in[15];
    const float* bwb2 = (const float*)d_in[16];
    const float* bwW3 = (const float*)d_in[17];
    const float* bwb3 = (const float*)d_in[18];
    const float* nuW  = (const float*)d_in[19];
    const float* nub  = (const float*)d_in[20];
    const float* lng  = (const float*)d_in[21];
    const float* lnb  = (const float*)d_in[22];

    // workspace layout (bytes):
    //   agg    [2*N*128] f32 : 51,200,000   @ 0
    //   tws    [2*N*128] bf16: 25,600,000   @ 51,200,000
    //   bws    [2*N]     f32 :    400,000   @ 76,800,000
    //   deg    [2*N]     i32 :    400,000   @ 77,200,000
    //   rowptr [2*N]     i32 :    400,000   @ 77,600,000
    //   cursor [2*N]     i32 :    400,000   @ 78,000,000
    //   esrc   [2*E]     i32 :  6,400,000   @ 78,400,000
    //   ecoef  [2*E]     f32 :  6,400,000   @ 84,800,000   total 91.2 MB
    char*  wsb    = (char*)d_ws;
    float* agg    = (float*)(wsb);
    u16*   tws    = (u16*)  (wsb + 51200000L);
    float* bws    = (float*)(wsb + 76800000L);
    int*   deg    = (int*)  (wsb + 77200000L);
    int*   rowptr = (int*)  (wsb + 77600000L);
    int*   cursor = (int*)  (wsb + 78000000L);
    int*   esrc   = (int*)  (wsb + 78400000L);
    float* ecoef  = (float*)(wsb + 84800000L);

    dim3 blk(256);
    k_zero<<<dim3((2 * NN + 255) / 256), blk, 0, stream>>>(deg, 2 * NN);

    dim3 g1((NN + 63) / 64, 2);
    k_boundary <<<g1, blk, 0, stream>>>(x, bdW1, bdb1, bdW2, bdb2, bdW3, bdb3, bws);
    k_edgetrans<<<g1, blk, 0, stream>>>(x, etW1, etb1, etW2, etb2, tws);

    dim3 ge(EE / 256, 2);    // 800000/256 = 3125 exactly
    k_hist <<<ge, blk, 0, stream>>>(ei, deg);
    k_scan <<<dim3(1, 2), blk, 0, stream>>>(deg, rowptr, cursor);
    k_place<<<ge, blk, 0, stream>>>(ei, ea, bwW1, bwb1, bwW2, bwb2, bwW3, bwb3,
                                    bws, cursor, esrc, ecoef);
    k_gather<<<dim3(NN / 4, 2), blk, 0, stream>>>(rowptr, deg, esrc, ecoef, tws, agg);

    k_final<<<g1, blk, 0, stream>>>(agg, x, nuW, nub, lng, lnb, (float*)d_out);
}

// Round 7
// 965.620 us; speedup vs baseline: 6.3757x; 1.3649x over previous
//
#include <hip/hip_runtime.h>

#define NN 50000
#define DD 128
#define EE 800000
#define THRV 0.3f

typedef unsigned short u16;

__device__ __forceinline__ float bf2f(u16 u){
    union { unsigned int i; float f; } v; v.i = ((unsigned int)u) << 16; return v.f;
}
__device__ __forceinline__ u16 f2bf(float f){
    unsigned int x = __float_as_uint(f);
    unsigned int r = (x + 0x7fffu + ((x >> 16) & 1u)) >> 16;
    return (u16)r;
}

// ---------------------------------------------------------------------------
// K0: zero the per-(et,dst) degree counters
// ---------------------------------------------------------------------------
__global__ __launch_bounds__(256)
void k_zero(int* p, int n)
{
    int i = blockIdx.x * 256 + threadIdx.x;
    if (i < n) p[i] = 0;
}

// ---------------------------------------------------------------------------
// K1: boundary MLP  b = sigmoid(relu(relu(x@W1+b1)@W2+b2)@W3+b3)   [2,N]
// All fp32 (the downstream >0.3 comparisons are discrete decisions).
// Staging is flat-float4 coalesced; LDS row stride 132 (16B-aligned rows).
// ---------------------------------------------------------------------------
__global__ __launch_bounds__(256)
void k_boundary(const float* x,
                const float* bdW1, const float* bdb1,
                const float* bdW2, const float* bdb2,
                const float* bdW3, const float* bdb3,
                float* bws)
{
    __shared__ __align__(16) char smem[59140];
    float* Xs  = (float*)(smem);           // [64][132] fp32 X tile
    float* H1  = (float*)(smem + 33792);   // [64][65]
    float* W2s = (float*)(smem + 50432);   // [64][32]
    float* W3s = (float*)(smem + 58624);   // [32]
    float* b2s = (float*)(smem + 58752);   // [32]
    float* b3s = (float*)(smem + 58880);   // [1]
    float* b1s = (float*)(smem + 58884);   // [64]
    float* H2s = (float*)(smem);           // [64][33], aliases Xs (dead after ph1)

    const int t  = threadIdx.x;
    const int et = blockIdx.y;
    const int R0 = blockIdx.x * 64;
    const int rowsLeft = NN - R0;

    {   // coalesced float4 staging: 64x128 = 2048 float4
        const float* xb = x + ((long)et * NN + R0) * DD;
        #pragma unroll
        for (int i = 0; i < 8; i++){
            int idx = i * 256 + t;
            int row = idx >> 5;
            int c4  = (idx & 31) << 2;
            float4 v = make_float4(0.f, 0.f, 0.f, 0.f);
            if (row < rowsLeft) v = *(const float4*)(xb + row * DD + c4);
            *(float4*)&Xs[row * 132 + c4] = v;
        }
    }
    if (t < 64) b1s[t] = bdb1[et * 64 + t];
    __syncthreads();

    // phase 1: H1[64][64] = relu(X @ W1 + b1); 16x16 threads, 4 rows x 4 cols
    const int tc = t & 15, tr = t >> 4;
    {
        const float* W1g = bdW1 + et * 8192;     // [128][64], L2-resident
        float acc[4][4];
        for (int m = 0; m < 4; m++)
            for (int j = 0; j < 4; j++) acc[m][j] = 0.0f;
        for (int k = 0; k < 128; k++){
            float4 wv = *(const float4*)(W1g + k * 64 + tc * 4);
            float xv[4];
            #pragma unroll
            for (int m = 0; m < 4; m++) xv[m] = Xs[(tr + 16 * m) * 132 + k];
            #pragma unroll
            for (int m = 0; m < 4; m++){
                acc[m][0] += xv[m] * wv.x;
                acc[m][1] += xv[m] * wv.y;
                acc[m][2] += xv[m] * wv.z;
                acc[m][3] += xv[m] * wv.w;
            }
        }
        for (int m = 0; m < 4; m++)
            for (int j = 0; j < 4; j++){
                int row = tr + 16 * m, col = tc * 4 + j;
                float v = acc[m][j] + b1s[col];
                H1[row * 65 + col] = v > 0.0f ? v : 0.0f;
            }
    }
    // stage W2/W3/b2/b3
    for (int idx = t; idx < 2048; idx += 256)
        W2s[idx] = bdW2[et * 2048 + idx];         // [64][32]
    if (t < 32){
        W3s[t] = bdW3[et * 32 + t];
        b2s[t] = bdb2[et * 32 + t];
    }
    if (t == 0) b3s[0] = bdb3[et];
    __syncthreads();

    // phase 2: H2[64][32] = relu(H1 @ W2 + b2); 32 cols x 8 thread-rows
    {
        int c2 = t & 31, r2 = t >> 5;
        float a2[8];
        for (int i = 0; i < 8; i++) a2[i] = b2s[c2];
        for (int k = 0; k < 64; k++){
            float wv = W2s[k * 32 + c2];
            #pragma unroll
            for (int i = 0; i < 8; i++)
                a2[i] += H1[(r2 + 8 * i) * 65 + k] * wv;
        }
        for (int i = 0; i < 8; i++)
            H2s[(r2 + 8 * i) * 33 + c2] = a2[i] > 0.0f ? a2[i] : 0.0f;
    }
    __syncthreads();

    // phase 3: dot-32 + sigmoid
    if (t < 64){
        float z = b3s[0];
        for (int j = 0; j < 32; j++)
            z += H2s[t * 33 + j] * W3s[j];
        float b = 1.0f / (1.0f + expf(-z));
        int row = R0 + t;
        if (row < NN) bws[et * NN + row] = b;
    }
}

// ---------------------------------------------------------------------------
// K2: edge transform  t = relu(x@W1+b1)@W2+b2  -> bf16 [2,N,128] in workspace
// ---------------------------------------------------------------------------
__global__ __launch_bounds__(256)
void k_edgetrans(const float* x,
                 const float* etW1, const float* etb1,
                 const float* etW2, const float* etb2,
                 u16* tws)
{
    __shared__ __align__(16) float Xs[64 * 132];   // X, then H
    __shared__ float b1s[128];
    __shared__ float b2s[128];

    const int t  = threadIdx.x;
    const int et = blockIdx.y;
    const int R0 = blockIdx.x * 64;
    const int rowsLeft = NN - R0;

    {   // coalesced float4 staging
        const float* xb = x + ((long)et * NN + R0) * DD;
        #pragma unroll
        for (int i = 0; i < 8; i++){
            int idx = i * 256 + t;
            int row = idx >> 5;
            int c4  = (idx & 31) << 2;
            float4 v = make_float4(0.f, 0.f, 0.f, 0.f);
            if (row < rowsLeft) v = *(const float4*)(xb + row * DD + c4);
            *(float4*)&Xs[row * 132 + c4] = v;
        }
    }
    if (t < 128) b1s[t] = etb1[et * 128 + t];
    else         b2s[t - 128] = etb2[et * 128 + (t - 128)];
    __syncthreads();

    const int tc = t & 15, tr = t >> 4;   // 16x16 threads; 4 rows x 8 cols each
    const float* W1g = etW1 + et * 16384;  // [128][128], L2-resident
    float acc[4][8];
    for (int m = 0; m < 4; m++)
        for (int j = 0; j < 8; j++) acc[m][j] = 0.0f;
    for (int k = 0; k < 128; k++){
        float4 wv0 = *(const float4*)(W1g + k * 128 + tc * 8);
        float4 wv1 = *(const float4*)(W1g + k * 128 + tc * 8 + 4);
        float xv[4];
        #pragma unroll
        for (int m = 0; m < 4; m++) xv[m] = Xs[(tr + 16 * m) * 132 + k];
        #pragma unroll
        for (int m = 0; m < 4; m++){
            acc[m][0] += xv[m] * wv0.x; acc[m][1] += xv[m] * wv0.y;
            acc[m][2] += xv[m] * wv0.z; acc[m][3] += xv[m] * wv0.w;
            acc[m][4] += xv[m] * wv1.x; acc[m][5] += xv[m] * wv1.y;
            acc[m][6] += xv[m] * wv1.z; acc[m][7] += xv[m] * wv1.w;
        }
    }
    __syncthreads();   // all reads of Xs done before overwrite

    // H = relu(acc + b1) into Xs (float4 stores)
    for (int m = 0; m < 4; m++){
        int row = tr + 16 * m;
        float4 h0, h1;
        h0.x = acc[m][0] + b1s[tc * 8 + 0]; h0.y = acc[m][1] + b1s[tc * 8 + 1];
        h0.z = acc[m][2] + b1s[tc * 8 + 2]; h0.w = acc[m][3] + b1s[tc * 8 + 3];
        h1.x = acc[m][4] + b1s[tc * 8 + 4]; h1.y = acc[m][5] + b1s[tc * 8 + 5];
        h1.z = acc[m][6] + b1s[tc * 8 + 6]; h1.w = acc[m][7] + b1s[tc * 8 + 7];
        h0.x = h0.x > 0.f ? h0.x : 0.f; h0.y = h0.y > 0.f ? h0.y : 0.f;
        h0.z = h0.z > 0.f ? h0.z : 0.f; h0.w = h0.w > 0.f ? h0.w : 0.f;
        h1.x = h1.x > 0.f ? h1.x : 0.f; h1.y = h1.y > 0.f ? h1.y : 0.f;
        h1.z = h1.z > 0.f ? h1.z : 0.f; h1.w = h1.w > 0.f ? h1.w : 0.f;
        *(float4*)&Xs[row * 132 + tc * 8]     = h0;
        *(float4*)&Xs[row * 132 + tc * 8 + 4] = h1;
    }
    __syncthreads();

    const float* W2g = etW2 + et * 16384;
    float acc2[4][8];
    for (int m = 0; m < 4; m++)
        for (int j = 0; j < 8; j++) acc2[m][j] = 0.0f;
    for (int k = 0; k < 128; k++){
        float4 wv0 = *(const float4*)(W2g + k * 128 + tc * 8);
        float4 wv1 = *(const float4*)(W2g + k * 128 + tc * 8 + 4);
        float xv[4];
        #pragma unroll
        for (int m = 0; m < 4; m++) xv[m] = Xs[(tr + 16 * m) * 132 + k];
        #pragma unroll
        for (int m = 0; m < 4; m++){
            acc2[m][0] += xv[m] * wv0.x; acc2[m][1] += xv[m] * wv0.y;
            acc2[m][2] += xv[m] * wv0.z; acc2[m][3] += xv[m] * wv0.w;
            acc2[m][4] += xv[m] * wv1.x; acc2[m][5] += xv[m] * wv1.y;
            acc2[m][6] += xv[m] * wv1.z; acc2[m][7] += xv[m] * wv1.w;
        }
    }
    for (int m = 0; m < 4; m++){
        int row = R0 + tr + 16 * m;
        if (row < NN){
            union { u16 us[8]; uint4 u4; } pk;
            #pragma unroll
            for (int j = 0; j < 8; j++)
                pk.us[j] = f2bf(acc2[m][j] + b2s[tc * 8 + j]);
            *(uint4*)(tws + ((long)et * NN + row) * DD + tc * 8) = pk.u4;
        }
    }
}

// ---------------------------------------------------------------------------
// K3: histogram of edges by dst:  deg[et][dst]++
// ---------------------------------------------------------------------------
__global__ __launch_bounds__(256)
void k_hist(const int* ei, int* deg)
{
    const int et = blockIdx.y;
    int e = blockIdx.x * 256 + threadIdx.x;
    int dst = ei[(et * 2 + 1) * EE + e];
    atomicAdd(&deg[et * NN + dst], 1);
}

// ---------------------------------------------------------------------------
// K4: exclusive scan of deg -> rowptr (and cursor copy); 1 block per et
// ---------------------------------------------------------------------------
__global__ __launch_bounds__(256)
void k_scan(const int* deg, int* rowptr, int* cursor)
{
    __shared__ int buf[256];
    __shared__ int carry;
    const int et = blockIdx.y;
    const int t  = threadIdx.x;
    if (t == 0) carry = 0;
    __syncthreads();
    for (int base = 0; base < NN; base += 256){
        int i = base + t;
        int v = (i < NN) ? deg[et * NN + i] : 0;
        buf[t] = v;
        __syncthreads();
        #pragma unroll
        for (int off = 1; off < 256; off <<= 1){
            int xv = (t >= off) ? buf[t - off] : 0;
            __syncthreads();
            buf[t] += xv;
            __syncthreads();
        }
        int incl = buf[t];
        int excl = incl - v + carry;
        if (i < NN){
            rowptr[et * NN + i] = excl;
            cursor[et * NN + i] = excl;
        }
        __syncthreads();
        if (t == 255) carry = excl + v;
        __syncthreads();
    }
}

// ---------------------------------------------------------------------------
// K5: per-edge coefficient MLP + CSR placement
// ---------------------------------------------------------------------------
__global__ __launch_bounds__(256)
void k_place(const int* ei, const float* ea,
             const float* bwW1, const float* bwb1,
             const float* bwW2, const float* bwb2,
             const float* bwW3, const float* bwb3,
             const float* bws, int* cursor,
             int* esrc, float* ecoef)
{
    __shared__ float W1s[64];
    __shared__ float b1sh[32];
    __shared__ float W2s[512];
    __shared__ float b2sh[16];
    __shared__ float W3s[16];
    __shared__ float b3sh[1];
    const int t  = threadIdx.x;
    const int et = blockIdx.y;

    if (t < 64)        W1s[t]        = bwW1[et * 64 + t];
    else if (t < 96)   b1sh[t - 64]  = bwb1[et * 32 + (t - 64)];
    else if (t < 112)  b2sh[t - 96]  = bwb2[et * 16 + (t - 96)];
    else if (t < 128)  W3s[t - 112]  = bwW3[et * 16 + (t - 112)];
    else if (t == 128) b3sh[0]       = bwb3[et];
    for (int idx = t; idx < 512; idx += 256)
        W2s[idx] = bwW2[et * 512 + idx];
    __syncthreads();

    int e   = blockIdx.x * 256 + t;
    int src = ei[(et * 2 + 0) * EE + e];
    int dst = ei[(et * 2 + 1) * EE + e];
    float sb = bws[et * NN + src];
    float db = bws[(1 - et) * NN + dst];

    float h1[32];
    #pragma unroll
    for (int j = 0; j < 32; j++){
        float v = sb * W1s[j] + db * W1s[32 + j] + b1sh[j];
        h1[j] = v > 0.0f ? v : 0.0f;
    }
    float h2[16];
    #pragma unroll
    for (int k = 0; k < 16; k++) h2[k] = b2sh[k];
    #pragma unroll
    for (int j = 0; j < 32; j++){
        float hv = h1[j];
        #pragma unroll
        for (int k = 0; k < 16; k++)
            h2[k] += hv * W2s[j * 16 + k];
    }
    float z = b3sh[0];
    #pragma unroll
    for (int k = 0; k < 16; k++){
        float hv = h2[k] > 0.0f ? h2[k] : 0.0f;
        z += hv * W3s[k];
    }
    float wv = 1.0f / (1.0f + expf(-z));
    if (sb > THRV || db > THRV) wv *= 2.0f;
    float c = ea[et * EE + e] * wv;

    int pos = atomicAdd(&cursor[et * NN + dst], 1);
    esrc [(long)et * EE + pos] = src;
    ecoef[(long)et * EE + pos] = c;
}

// ---------------------------------------------------------------------------
// K6: CSR gather — one wave per dst node, 2 dims per lane, fp32 registers.
// ---------------------------------------------------------------------------
__global__ __launch_bounds__(256)
void k_gather(const int* rowptr, const int* deg,
              const int* esrc, const float* ecoef,
              const u16* tws, float* agg)
{
    const int et   = blockIdx.y;
    const int w    = threadIdx.x >> 6;
    const int lane = threadIdx.x & 63;
    const int n    = blockIdx.x * 4 + w;          // 12500*4 = 50000 exactly

    int start = rowptr[et * NN + n];
    int cnt   = deg[et * NN + n];
    const int*   es = esrc  + (long)et * EE + start;
    const float* ec = ecoef + (long)et * EE + start;

    float a0 = 0.0f, a1 = 0.0f;
    for (int k = 0; k < cnt; k++){
        int   src = es[k];
        float c   = ec[k];
        unsigned int pv = *(const unsigned int*)(tws + ((long)et * NN + src) * DD + lane * 2);
        a0 += bf2f((u16)(pv & 0xffffu)) * c;
        a1 += bf2f((u16)(pv >> 16)) * c;
    }
    float* op = agg + ((long)(1 - et) * NN + n) * DD + lane * 2;
    op[0] = a0;
    op[1] = a1;
}

// ---------------------------------------------------------------------------
// K7: U = agg + x; z = U@nuW + nub; LayerNorm; relu -> out fp32
// LN fully in registers via shfl across the 16 tc-lanes of each row.
// ---------------------------------------------------------------------------
__global__ __launch_bounds__(256)
void k_final(const float* agg, const float* x,
             const float* nuW, const float* nub,
             const float* lng, const float* lnb,
             float* out)
{
    __shared__ __align__(16) float Us[64 * 132];
    __shared__ float nubs[128], lngs[128], lnbs[128];

    const int t  = threadIdx.x;
    const int et = blockIdx.y;
    const int R0 = blockIdx.x * 64;
    const int rowsLeft = NN - R0;

    {   // coalesced float4 staging of U = agg + x
        const float* xb = x   + ((long)et * NN + R0) * DD;
        const float* ab = agg + ((long)et * NN + R0) * DD;
        #pragma unroll
        for (int i = 0; i < 8; i++){
            int idx = i * 256 + t;
            int row = idx >> 5;
            int c4  = (idx & 31) << 2;
            float4 v = make_float4(0.f, 0.f, 0.f, 0.f);
            if (row < rowsLeft){
                float4 xv4 = *(const float4*)(xb + row * DD + c4);
                float4 av4 = *(const float4*)(ab + row * DD + c4);
                v.x = xv4.x + av4.x; v.y = xv4.y + av4.y;
                v.z = xv4.z + av4.z; v.w = xv4.w + av4.w;
            }
            *(float4*)&Us[row * 132 + c4] = v;
        }
    }
    if (t < 128) nubs[t] = nub[et * 128 + t];
    else {
        lngs[t - 128] = lng[et * 128 + (t - 128)];
        lnbs[t - 128] = lnb[et * 128 + (t - 128)];
    }
    __syncthreads();

    const int tc = t & 15, tr = t >> 4;
    const float* Wg = nuW + et * 16384;    // [128][128], L2-resident
    float acc[4][8];
    for (int m = 0; m < 4; m++)
        for (int j = 0; j < 8; j++) acc[m][j] = 0.0f;
    for (int k = 0; k < 128; k++){
        float4 wv0 = *(const float4*)(Wg + k * 128 + tc * 8);
        float4 wv1 = *(const float4*)(Wg + k * 128 + tc * 8 + 4);
        float xv[4];
        #pragma unroll
        for (int m = 0; m < 4; m++) xv[m] = Us[(tr + 16 * m) * 132 + k];
        #pragma unroll
        for (int m = 0; m < 4; m++){
            acc[m][0] += xv[m] * wv0.x; acc[m][1] += xv[m] * wv0.y;
            acc[m][2] += xv[m] * wv0.z; acc[m][3] += xv[m] * wv0.w;
            acc[m][4] += xv[m] * wv1.x; acc[m][5] += xv[m] * wv1.y;
            acc[m][6] += xv[m] * wv1.z; acc[m][7] += xv[m] * wv1.w;
        }
    }

    // z = acc + nub; in-register LayerNorm per row (16 tc-lanes hold a row)
    for (int m = 0; m < 4; m++){
        float z[8];
        float s = 0.0f, ss = 0.0f;
        #pragma unroll
        for (int j = 0; j < 8; j++){
            z[j] = acc[m][j] + nubs[tc * 8 + j];
            s += z[j]; ss += z[j] * z[j];
        }
        s  += __shfl_xor(s, 1);  s  += __shfl_xor(s, 2);
        s  += __shfl_xor(s, 4);  s  += __shfl_xor(s, 8);
        ss += __shfl_xor(ss, 1); ss += __shfl_xor(ss, 2);
        ss += __shfl_xor(ss, 4); ss += __shfl_xor(ss, 8);
        float mean = s * (1.0f / 128.0f);
        float var  = ss * (1.0f / 128.0f) - mean * mean;
        float rstd = rsqrtf(var + 1e-5f);
        int grow = R0 + tr + 16 * m;
        if (grow < NN){
            float4 o0, o1;
            float o[8];
            #pragma unroll
            for (int j = 0; j < 8; j++){
                int col = tc * 8 + j;
                float v = (z[j] - mean) * rstd * lngs[col] + lnbs[col];
                o[j] = v > 0.0f ? v : 0.0f;
            }
            o0.x = o[0]; o0.y = o[1]; o0.z = o[2]; o0.w = o[3];
            o1.x = o[4]; o1.y = o[5]; o1.z = o[6]; o1.w = o[7];
            float* op = out + ((long)et * NN + grow) * DD + tc * 8;
            *(float4*)(op)     = o0;
            *(float4*)(op + 4) = o1;
        }
    }
}

// ---------------------------------------------------------------------------
extern "C" void kernel_launch(void* const* d_in, const int* in_sizes, int n_in,
                              void* d_out, int out_size, void* d_ws, size_t ws_size,
                              hipStream_t stream)
{
    const float* x    = (const float*)d_in[0];
    const int*   ei   = (const int*)d_in[1];
    const float* ea   = (const float*)d_in[2];
    const float* bdW1 = (const float*)d_in[3];
    const float* bdb1 = (const float*)d_in[4];
    const float* bdW2 = (const float*)d_in[5];
    const float* bdb2 = (const float*)d_in[6];
    const float* bdW3 = (const float*)d_in[7];
    const float* bdb3 = (const float*)d_in[8];
    const float* etW1 = (const float*)d_in[9];
    const float* etb1 = (const float*)d_in[10];
    const float* etW2 = (const float*)d_in[11];
    const float* etb2 = (const float*)d_in[12];
    const float* bwW1 = (const float*)d_in[13];
    const float* bwb1 = (const float*)d_in[14];
    const float* bwW2 = (const float*)d_in[15];
    const float* bwb2 = (const float*)d_in[16];
    const float* bwW3 = (const float*)d_in[17];
    const float* bwb3 = (const float*)d_in[18];
    const float* nuW  = (const float*)d_in[19];
    const float* nub  = (const float*)d_in[20];
    const float* lng  = (const float*)d_in[21];
    const float* lnb  = (const float*)d_in[22];

    // workspace layout (bytes):
    //   agg    [2*N*128] f32 : 51,200,000   @ 0
    //   tws    [2*N*128] bf16: 25,600,000   @ 51,200,000
    //   bws    [2*N]     f32 :    400,000   @ 76,800,000
    //   deg    [2*N]     i32 :    400,000   @ 77,200,000
    //   rowptr [2*N]     i32 :    400,000   @ 77,600,000
    //   cursor [2*N]     i32 :    400,000   @ 78,000,000
    //   esrc   [2*E]     i32 :  6,400,000   @ 78,400,000
    //   ecoef  [2*E]     f32 :  6,400,000   @ 84,800,000   total 91.2 MB
    char*  wsb    = (char*)d_ws;
    float* agg    = (float*)(wsb);
    u16*   tws    = (u16*)  (wsb + 51200000L);
    float* bws    = (float*)(wsb + 76800000L);
    int*   deg    = (int*)  (wsb + 77200000L);
    int*   rowptr = (int*)  (wsb + 77600000L);
    int*   cursor = (int*)  (wsb + 78000000L);
    int*   esrc   = (int*)  (wsb + 78400000L);
    float* ecoef  = (float*)(wsb + 84800000L);

    dim3 blk(256);
    k_zero<<<dim3((2 * NN + 255) / 256), blk, 0, stream>>>(deg, 2 * NN);

    dim3 g1((NN + 63) / 64, 2);
    k_boundary <<<g1, blk, 0, stream>>>(x, bdW1, bdb1, bdW2, bdb2, bdW3, bdb3, bws);
    k_edgetrans<<<g1, blk, 0, stream>>>(x, etW1, etb1, etW2, etb2, tws);

    dim3 ge(EE / 256, 2);    // 800000/256 = 3125 exactly
    k_hist <<<ge, blk, 0, stream>>>(ei, deg);
    k_scan <<<dim3(1, 2), blk, 0, stream>>>(deg, rowptr, cursor);
    k_place<<<ge, blk, 0, stream>>>(ei, ea, bwW1, bwb1, bwW2, bwb2, bwW3, bwb3,
                                    bws, cursor, esrc, ecoef);
    k_gather<<<dim3(NN / 4, 2), blk, 0, stream>>>(rowptr, deg, esrc, ecoef, tws, agg);

    k_final<<<g1, blk, 0, stream>>>(agg, x, nuW, nub, lng, lnb, (float*)d_out);
}

// Round 8
// 762.872 us; speedup vs baseline: 8.0702x; 1.2658x over previous
//
#include <hip/hip_runtime.h>

#define NN 50000
#define DD 128
#define EE 800000
#define THRV 0.3f
#define SCAN_BLK 25           // ceil(50000 / 2048)

typedef unsigned short u16;

__device__ __forceinline__ float bf2f(u16 u){
    union { unsigned int i; float f; } v; v.i = ((unsigned int)u) << 16; return v.f;
}
__device__ __forceinline__ u16 f2bf(float f){
    unsigned int x = __float_as_uint(f);
    unsigned int r = (x + 0x7fffu + ((x >> 16) & 1u)) >> 16;
    return (u16)r;
}

// ---------------------------------------------------------------------------
// K0: zero the per-(et,dst) degree counters
// ---------------------------------------------------------------------------
__global__ __launch_bounds__(256)
void k_zero(int* p, int n)
{
    int i = blockIdx.x * 256 + threadIdx.x;
    if (i < n) p[i] = 0;
}

// ---------------------------------------------------------------------------
// K1: boundary MLP  b = sigmoid(relu(relu(x@W1+b1)@W2+b2)@W3+b3)   [2,N]
// ---------------------------------------------------------------------------
__global__ __launch_bounds__(256)
void k_boundary(const float* x,
                const float* bdW1, const float* bdb1,
                const float* bdW2, const float* bdb2,
                const float* bdW3, const float* bdb3,
                float* bws)
{
    __shared__ __align__(16) char smem[59140];
    float* Xs  = (float*)(smem);           // [64][132] fp32 X tile
    float* H1  = (float*)(smem + 33792);   // [64][65]
    float* W2s = (float*)(smem + 50432);   // [64][32]
    float* W3s = (float*)(smem + 58624);   // [32]
    float* b2s = (float*)(smem + 58752);   // [32]
    float* b3s = (float*)(smem + 58880);   // [1]
    float* b1s = (float*)(smem + 58884);   // [64]
    float* H2s = (float*)(smem);           // [64][33], aliases Xs (dead after ph1)

    const int t  = threadIdx.x;
    const int et = blockIdx.y;
    const int R0 = blockIdx.x * 64;
    const int rowsLeft = NN - R0;

    {   // coalesced float4 staging: 64x128 = 2048 float4
        const float* xb = x + ((long)et * NN + R0) * DD;
        #pragma unroll
        for (int i = 0; i < 8; i++){
            int idx = i * 256 + t;
            int row = idx >> 5;
            int c4  = (idx & 31) << 2;
            float4 v = make_float4(0.f, 0.f, 0.f, 0.f);
            if (row < rowsLeft) v = *(const float4*)(xb + row * DD + c4);
            *(float4*)&Xs[row * 132 + c4] = v;
        }
    }
    if (t < 64) b1s[t] = bdb1[et * 64 + t];
    __syncthreads();

    // phase 1: H1[64][64] = relu(X @ W1 + b1); 16x16 threads, 4 rows x 4 cols
    const int tc = t & 15, tr = t >> 4;
    {
        const float* W1g = bdW1 + et * 8192;     // [128][64], L2-resident
        float acc[4][4];
        for (int m = 0; m < 4; m++)
            for (int j = 0; j < 4; j++) acc[m][j] = 0.0f;
        for (int k = 0; k < 128; k++){
            float4 wv = *(const float4*)(W1g + k * 64 + tc * 4);
            float xv[4];
            #pragma unroll
            for (int m = 0; m < 4; m++) xv[m] = Xs[(tr + 16 * m) * 132 + k];
            #pragma unroll
            for (int m = 0; m < 4; m++){
                acc[m][0] += xv[m] * wv.x;
                acc[m][1] += xv[m] * wv.y;
                acc[m][2] += xv[m] * wv.z;
                acc[m][3] += xv[m] * wv.w;
            }
        }
        for (int m = 0; m < 4; m++)
            for (int j = 0; j < 4; j++){
                int row = tr + 16 * m, col = tc * 4 + j;
                float v = acc[m][j] + b1s[col];
                H1[row * 65 + col] = v > 0.0f ? v : 0.0f;
            }
    }
    // stage W2/W3/b2/b3
    for (int idx = t; idx < 2048; idx += 256)
        W2s[idx] = bdW2[et * 2048 + idx];         // [64][32]
    if (t < 32){
        W3s[t] = bdW3[et * 32 + t];
        b2s[t] = bdb2[et * 32 + t];
    }
    if (t == 0) b3s[0] = bdb3[et];
    __syncthreads();

    // phase 2: H2[64][32] = relu(H1 @ W2 + b2); 32 cols x 8 thread-rows
    {
        int c2 = t & 31, r2 = t >> 5;
        float a2[8];
        for (int i = 0; i < 8; i++) a2[i] = b2s[c2];
        for (int k = 0; k < 64; k++){
            float wv = W2s[k * 32 + c2];
            #pragma unroll
            for (int i = 0; i < 8; i++)
                a2[i] += H1[(r2 + 8 * i) * 65 + k] * wv;
        }
        for (int i = 0; i < 8; i++)
            H2s[(r2 + 8 * i) * 33 + c2] = a2[i] > 0.0f ? a2[i] : 0.0f;
    }
    __syncthreads();

    // phase 3: dot-32 + sigmoid
    if (t < 64){
        float z = b3s[0];
        for (int j = 0; j < 32; j++)
            z += H2s[t * 33 + j] * W3s[j];
        float b = 1.0f / (1.0f + expf(-z));
        int row = R0 + t;
        if (row < NN) bws[et * NN + row] = b;
    }
}

// ---------------------------------------------------------------------------
// K2: edge transform  t = relu(x@W1+b1)@W2+b2  -> bf16 [2,N,128] in workspace
// ---------------------------------------------------------------------------
__global__ __launch_bounds__(256)
void k_edgetrans(const float* x,
                 const float* etW1, const float* etb1,
                 const float* etW2, const float* etb2,
                 u16* tws)
{
    __shared__ __align__(16) float Xs[64 * 132];   // X, then H
    __shared__ float b1s[128];
    __shared__ float b2s[128];

    const int t  = threadIdx.x;
    const int et = blockIdx.y;
    const int R0 = blockIdx.x * 64;
    const int rowsLeft = NN - R0;

    {   // coalesced float4 staging
        const float* xb = x + ((long)et * NN + R0) * DD;
        #pragma unroll
        for (int i = 0; i < 8; i++){
            int idx = i * 256 + t;
            int row = idx >> 5;
            int c4  = (idx & 31) << 2;
            float4 v = make_float4(0.f, 0.f, 0.f, 0.f);
            if (row < rowsLeft) v = *(const float4*)(xb + row * DD + c4);
            *(float4*)&Xs[row * 132 + c4] = v;
        }
    }
    if (t < 128) b1s[t] = etb1[et * 128 + t];
    else         b2s[t - 128] = etb2[et * 128 + (t - 128)];
    __syncthreads();

    const int tc = t & 15, tr = t >> 4;   // 16x16 threads; 4 rows x 8 cols each
    const float* W1g = etW1 + et * 16384;  // [128][128], L2-resident
    float acc[4][8];
    for (int m = 0; m < 4; m++)
        for (int j = 0; j < 8; j++) acc[m][j] = 0.0f;
    for (int k = 0; k < 128; k++){
        float4 wv0 = *(const float4*)(W1g + k * 128 + tc * 8);
        float4 wv1 = *(const float4*)(W1g + k * 128 + tc * 8 + 4);
        float xv[4];
        #pragma unroll
        for (int m = 0; m < 4; m++) xv[m] = Xs[(tr + 16 * m) * 132 + k];
        #pragma unroll
        for (int m = 0; m < 4; m++){
            acc[m][0] += xv[m] * wv0.x; acc[m][1] += xv[m] * wv0.y;
            acc[m][2] += xv[m] * wv0.z; acc[m][3] += xv[m] * wv0.w;
            acc[m][4] += xv[m] * wv1.x; acc[m][5] += xv[m] * wv1.y;
            acc[m][6] += xv[m] * wv1.z; acc[m][7] += xv[m] * wv1.w;
        }
    }
    __syncthreads();   // all reads of Xs done before overwrite

    // H = relu(acc + b1) into Xs (float4 stores)
    for (int m = 0; m < 4; m++){
        int row = tr + 16 * m;
        float4 h0, h1;
        h0.x = acc[m][0] + b1s[tc * 8 + 0]; h0.y = acc[m][1] + b1s[tc * 8 + 1];
        h0.z = acc[m][2] + b1s[tc * 8 + 2]; h0.w = acc[m][3] + b1s[tc * 8 + 3];
        h1.x = acc[m][4] + b1s[tc * 8 + 4]; h1.y = acc[m][5] + b1s[tc * 8 + 5];
        h1.z = acc[m][6] + b1s[tc * 8 + 6]; h1.w = acc[m][7] + b1s[tc * 8 + 7];
        h0.x = h0.x > 0.f ? h0.x : 0.f; h0.y = h0.y > 0.f ? h0.y : 0.f;
        h0.z = h0.z > 0.f ? h0.z : 0.f; h0.w = h0.w > 0.f ? h0.w : 0.f;
        h1.x = h1.x > 0.f ? h1.x : 0.f; h1.y = h1.y > 0.f ? h1.y : 0.f;
        h1.z = h1.z > 0.f ? h1.z : 0.f; h1.w = h1.w > 0.f ? h1.w : 0.f;
        *(float4*)&Xs[row * 132 + tc * 8]     = h0;
        *(float4*)&Xs[row * 132 + tc * 8 + 4] = h1;
    }
    __syncthreads();

    const float* W2g = etW2 + et * 16384;
    float acc2[4][8];
    for (int m = 0; m < 4; m++)
        for (int j = 0; j < 8; j++) acc2[m][j] = 0.0f;
    for (int k = 0; k < 128; k++){
        float4 wv0 = *(const float4*)(W2g + k * 128 + tc * 8);
        float4 wv1 = *(const float4*)(W2g + k * 128 + tc * 8 + 4);
        float xv[4];
        #pragma unroll
        for (int m = 0; m < 4; m++) xv[m] = Xs[(tr + 16 * m) * 132 + k];
        #pragma unroll
        for (int m = 0; m < 4; m++){
            acc2[m][0] += xv[m] * wv0.x; acc2[m][1] += xv[m] * wv0.y;
            acc2[m][2] += xv[m] * wv0.z; acc2[m][3] += xv[m] * wv0.w;
            acc2[m][4] += xv[m] * wv1.x; acc2[m][5] += xv[m] * wv1.y;
            acc2[m][6] += xv[m] * wv1.z; acc2[m][7] += xv[m] * wv1.w;
        }
    }
    for (int m = 0; m < 4; m++){
        int row = R0 + tr + 16 * m;
        if (row < NN){
            union { u16 us[8]; uint4 u4; } pk;
            #pragma unroll
            for (int j = 0; j < 8; j++)
                pk.us[j] = f2bf(acc2[m][j] + b2s[tc * 8 + j]);
            *(uint4*)(tws + ((long)et * NN + row) * DD + tc * 8) = pk.u4;
        }
    }
}

// ---------------------------------------------------------------------------
// K3: histogram of edges by dst:  deg[et][dst]++
// ---------------------------------------------------------------------------
__global__ __launch_bounds__(256)
void k_hist(const int* ei, int* deg)
{
    const int et = blockIdx.y;
    int e = blockIdx.x * 256 + threadIdx.x;
    int dst = ei[(et * 2 + 1) * EE + e];
    atomicAdd(&deg[et * NN + dst], 1);
}

// ---------------------------------------------------------------------------
// K4a: local scan — each block scans 2048 elems (8/thread serial + 256-wide
// Hillis-Steele); writes local-exclusive values to rowptr, block total to bsum
// ---------------------------------------------------------------------------
__global__ __launch_bounds__(256)
void k_scan_local(const int* deg, int* rowptr, int* bsum)
{
    __shared__ int tsum[256];
    const int et  = blockIdx.y;
    const int blk = blockIdx.x;
    const int t   = threadIdx.x;
    const int base = blk * 2048 + t * 8;

    int v[8];
    int run = 0;
    #pragma unroll
    for (int j = 0; j < 8; j++){
        int i = base + j;
        int d = (i < NN) ? deg[et * NN + i] : 0;
        v[j] = run;            // thread-local exclusive prefix
        run += d;
    }
    tsum[t] = run;
    __syncthreads();
    #pragma unroll
    for (int off = 1; off < 256; off <<= 1){
        int a = (t >= off) ? tsum[t - off] : 0;
        __syncthreads();
        tsum[t] += a;
        __syncthreads();
    }
    int excl = tsum[t] - run;   // exclusive prefix of this thread within block
    #pragma unroll
    for (int j = 0; j < 8; j++){
        int i = base + j;
        if (i < NN) rowptr[et * NN + i] = excl + v[j];
    }
    if (t == 255) bsum[et * SCAN_BLK + blk] = tsum[255];
}

// ---------------------------------------------------------------------------
// K4b: scan the 25 block sums per et (trivial, 1 block, 2 active threads)
// ---------------------------------------------------------------------------
__global__ __launch_bounds__(64)
void k_scan_bsum(int* bsum, int* boff)
{
    int et = threadIdx.x;
    if (et < 2){
        int run = 0;
        for (int b = 0; b < SCAN_BLK; b++){
            int d = bsum[et * SCAN_BLK + b];
            boff[et * SCAN_BLK + b] = run;
            run += d;
        }
    }
}

// ---------------------------------------------------------------------------
// K4c: add block offsets; emit final rowptr and cursor (coalesced)
// ---------------------------------------------------------------------------
__global__ __launch_bounds__(256)
void k_scan_add(int* rowptr, int* cursor, const int* boff)
{
    const int et  = blockIdx.y;
    const int blk = blockIdx.x;
    const int t   = threadIdx.x;
    const int off = boff[et * SCAN_BLK + blk];
    #pragma unroll
    for (int j = 0; j < 8; j++){
        int i = blk * 2048 + j * 256 + t;
        if (i < NN){
            int r = rowptr[et * NN + i] + off;
            rowptr[et * NN + i] = r;
            cursor[et * NN + i] = r;
        }
    }
}

// ---------------------------------------------------------------------------
// K5: per-edge coefficient MLP + CSR placement
// ---------------------------------------------------------------------------
__global__ __launch_bounds__(256)
void k_place(const int* ei, const float* ea,
             const float* bwW1, const float* bwb1,
             const float* bwW2, const float* bwb2,
             const float* bwW3, const float* bwb3,
             const float* bws, int* cursor,
             int* esrc, float* ecoef)
{
    __shared__ float W1s[64];
    __shared__ float b1sh[32];
    __shared__ float W2s[512];
    __shared__ float b2sh[16];
    __shared__ float W3s[16];
    __shared__ float b3sh[1];
    const int t  = threadIdx.x;
    const int et = blockIdx.y;

    if (t < 64)        W1s[t]        = bwW1[et * 64 + t];
    else if (t < 96)   b1sh[t - 64]  = bwb1[et * 32 + (t - 64)];
    else if (t < 112)  b2sh[t - 96]  = bwb2[et * 16 + (t - 96)];
    else if (t < 128)  W3s[t - 112]  = bwW3[et * 16 + (t - 112)];
    else if (t == 128) b3sh[0]       = bwb3[et];
    for (int idx = t; idx < 512; idx += 256)
        W2s[idx] = bwW2[et * 512 + idx];
    __syncthreads();

    int e   = blockIdx.x * 256 + t;
    int src = ei[(et * 2 + 0) * EE + e];
    int dst = ei[(et * 2 + 1) * EE + e];
    float sb = bws[et * NN + src];
    float db = bws[(1 - et) * NN + dst];

    float h1[32];
    #pragma unroll
    for (int j = 0; j < 32; j++){
        float v = sb * W1s[j] + db * W1s[32 + j] + b1sh[j];
        h1[j] = v > 0.0f ? v : 0.0f;
    }
    float h2[16];
    #pragma unroll
    for (int k = 0; k < 16; k++) h2[k] = b2sh[k];
    #pragma unroll
    for (int j = 0; j < 32; j++){
        float hv = h1[j];
        #pragma unroll
        for (int k = 0; k < 16; k++)
            h2[k] += hv * W2s[j * 16 + k];
    }
    float z = b3sh[0];
    #pragma unroll
    for (int k = 0; k < 16; k++){
        float hv = h2[k] > 0.0f ? h2[k] : 0.0f;
        z += hv * W3s[k];
    }
    float wv = 1.0f / (1.0f + expf(-z));
    if (sb > THRV || db > THRV) wv *= 2.0f;
    float c = ea[et * EE + e] * wv;

    int pos = atomicAdd(&cursor[et * NN + dst], 1);
    esrc [(long)et * EE + pos] = src;
    ecoef[(long)et * EE + pos] = c;
}

// ---------------------------------------------------------------------------
// K6: CSR gather — one wave per dst node, 2 dims per lane, fp32 registers.
// ---------------------------------------------------------------------------
__global__ __launch_bounds__(256)
void k_gather(const int* rowptr, const int* deg,
              const int* esrc, const float* ecoef,
              const u16* tws, float* agg)
{
    const int et   = blockIdx.y;
    const int w    = threadIdx.x >> 6;
    const int lane = threadIdx.x & 63;
    const int n    = blockIdx.x * 4 + w;          // 12500*4 = 50000 exactly

    int start = rowptr[et * NN + n];
    int cnt   = deg[et * NN + n];
    const int*   es = esrc  + (long)et * EE + start;
    const float* ec = ecoef + (long)et * EE + start;

    float a0 = 0.0f, a1 = 0.0f;
    for (int k = 0; k < cnt; k++){
        int   src = es[k];
        float c   = ec[k];
        unsigned int pv = *(const unsigned int*)(tws + ((long)et * NN + src) * DD + lane * 2);
        a0 += bf2f((u16)(pv & 0xffffu)) * c;
        a1 += bf2f((u16)(pv >> 16)) * c;
    }
    float* op = agg + ((long)(1 - et) * NN + n) * DD + lane * 2;
    op[0] = a0;
    op[1] = a1;
}

// ---------------------------------------------------------------------------
// K7: U = agg + x; z = U@nuW + nub; LayerNorm; relu -> out fp32
// ---------------------------------------------------------------------------
__global__ __launch_bounds__(256)
void k_final(const float* agg, const float* x,
             const float* nuW, const float* nub,
             const float* lng, const float* lnb,
             float* out)
{
    __shared__ __align__(16) float Us[64 * 132];
    __shared__ float nubs[128], lngs[128], lnbs[128];

    const int t  = threadIdx.x;
    const int et = blockIdx.y;
    const int R0 = blockIdx.x * 64;
    const int rowsLeft = NN - R0;

    {   // coalesced float4 staging of U = agg + x
        const float* xb = x   + ((long)et * NN + R0) * DD;
        const float* ab = agg + ((long)et * NN + R0) * DD;
        #pragma unroll
        for (int i = 0; i < 8; i++){
            int idx = i * 256 + t;
            int row = idx >> 5;
            int c4  = (idx & 31) << 2;
            float4 v = make_float4(0.f, 0.f, 0.f, 0.f);
            if (row < rowsLeft){
                float4 xv4 = *(const float4*)(xb + row * DD + c4);
                float4 av4 = *(const float4*)(ab + row * DD + c4);
                v.x = xv4.x + av4.x; v.y = xv4.y + av4.y;
                v.z = xv4.z + av4.z; v.w = xv4.w + av4.w;
            }
            *(float4*)&Us[row * 132 + c4] = v;
        }
    }
    if (t < 128) nubs[t] = nub[et * 128 + t];
    else {
        lngs[t - 128] = lng[et * 128 + (t - 128)];
        lnbs[t - 128] = lnb[et * 128 + (t - 128)];
    }
    __syncthreads();

    const int tc = t & 15, tr = t >> 4;
    const float* Wg = nuW + et * 16384;    // [128][128], L2-resident
    float acc[4][8];
    for (int m = 0; m < 4; m++)
        for (int j = 0; j < 8; j++) acc[m][j] = 0.0f;
    for (int k = 0; k < 128; k++){
        float4 wv0 = *(const float4*)(Wg + k * 128 + tc * 8);
        float4 wv1 = *(const float4*)(Wg + k * 128 + tc * 8 + 4);
        float xv[4];
        #pragma unroll
        for (int m = 0; m < 4; m++) xv[m] = Us[(tr + 16 * m) * 132 + k];
        #pragma unroll
        for (int m = 0; m < 4; m++){
            acc[m][0] += xv[m] * wv0.x; acc[m][1] += xv[m] * wv0.y;
            acc[m][2] += xv[m] * wv0.z; acc[m][3] += xv[m] * wv0.w;
            acc[m][4] += xv[m] * wv1.x; acc[m][5] += xv[m] * wv1.y;
            acc[m][6] += xv[m] * wv1.z; acc[m][7] += xv[m] * wv1.w;
        }
    }

    // z = acc + nub; in-register LayerNorm per row (16 tc-lanes hold a row)
    for (int m = 0; m < 4; m++){
        float z[8];
        float s = 0.0f, ss = 0.0f;
        #pragma unroll
        for (int j = 0; j < 8; j++){
            z[j] = acc[m][j] + nubs[tc * 8 + j];
            s += z[j]; ss += z[j] * z[j];
        }
        s  += __shfl_xor(s, 1);  s  += __shfl_xor(s, 2);
        s  += __shfl_xor(s, 4);  s  += __shfl_xor(s, 8);
        ss += __shfl_xor(ss, 1); ss += __shfl_xor(ss, 2);
        ss += __shfl_xor(ss, 4); ss += __shfl_xor(ss, 8);
        float mean = s * (1.0f / 128.0f);
        float var  = ss * (1.0f / 128.0f) - mean * mean;
        float rstd = rsqrtf(var + 1e-5f);
        int grow = R0 + tr + 16 * m;
        if (grow < NN){
            float4 o0, o1;
            float o[8];
            #pragma unroll
            for (int j = 0; j < 8; j++){
                int col = tc * 8 + j;
                float v = (z[j] - mean) * rstd * lngs[col] + lnbs[col];
                o[j] = v > 0.0f ? v : 0.0f;
            }
            o0.x = o[0]; o0.y = o[1]; o0.z = o[2]; o0.w = o[3];
            o1.x = o[4]; o1.y = o[5]; o1.z = o[6]; o1.w = o[7];
            float* op = out + ((long)et * NN + grow) * DD + tc * 8;
            *(float4*)(op)     = o0;
            *(float4*)(op + 4) = o1;
        }
    }
}

// ---------------------------------------------------------------------------
extern "C" void kernel_launch(void* const* d_in, const int* in_sizes, int n_in,
                              void* d_out, int out_size, void* d_ws, size_t ws_size,
                              hipStream_t stream)
{
    const float* x    = (const float*)d_in[0];
    const int*   ei   = (const int*)d_in[1];
    const float* ea   = (const float*)d_in[2];
    const float* bdW1 = (const float*)d_in[3];
    const float* bdb1 = (const float*)d_in[4];
    const float* bdW2 = (const float*)d_in[5];
    const float* bdb2 = (const float*)d_in[6];
    const float* bdW3 = (const float*)d_in[7];
    const float* bdb3 = (const float*)d_in[8];
    const float* etW1 = (const float*)d_in[9];
    const float* etb1 = (const float*)d_in[10];
    const float* etW2 = (const float*)d_in[11];
    const float* etb2 = (const float*)d_in[12];
    const float* bwW1 = (const float*)d_in[13];
    const float* bwb1 = (const float*)d_in[14];
    const float* bwW2 = (const float*)d_in[15];
    const float* bwb2 = (const float*)d_in[16];
    const float* bwW3 = (const float*)d_in[17];
    const float* bwb3 = (const float*)d_in[18];
    const float* nuW  = (const float*)d_in[19];
    const float* nub  = (const float*)d_in[20];
    const float* lng  = (const float*)d_in[21];
    const float* lnb  = (const float*)d_in[22];

    // workspace layout (bytes):
    //   agg    [2*N*128] f32 : 51,200,000   @ 0
    //   tws    [2*N*128] bf16: 25,600,000   @ 51,200,000
    //   bws    [2*N]     f32 :    400,000   @ 76,800,000
    //   deg    [2*N]     i32 :    400,000   @ 77,200,000
    //   rowptr [2*N]     i32 :    400,000   @ 77,600,000
    //   cursor [2*N]     i32 :    400,000   @ 78,000,000
    //   esrc   [2*E]     i32 :  6,400,000   @ 78,400,000
    //   ecoef  [2*E]     f32 :  6,400,000   @ 84,800,000
    //   bsum   [2*25]    i32 :        200   @ 91,200,000
    //   boff   [2*25]    i32 :        200   @ 91,200,512
    char*  wsb    = (char*)d_ws;
    float* agg    = (float*)(wsb);
    u16*   tws    = (u16*)  (wsb + 51200000L);
    float* bws    = (float*)(wsb + 76800000L);
    int*   deg    = (int*)  (wsb + 77200000L);
    int*   rowptr = (int*)  (wsb + 77600000L);
    int*   cursor = (int*)  (wsb + 78000000L);
    int*   esrc   = (int*)  (wsb + 78400000L);
    float* ecoef  = (float*)(wsb + 84800000L);
    int*   bsum   = (int*)  (wsb + 91200000L);
    int*   boff   = (int*)  (wsb + 91200512L);

    dim3 blk(256);
    k_zero<<<dim3((2 * NN + 255) / 256), blk, 0, stream>>>(deg, 2 * NN);

    dim3 g1((NN + 63) / 64, 2);
    k_boundary <<<g1, blk, 0, stream>>>(x, bdW1, bdb1, bdW2, bdb2, bdW3, bdb3, bws);
    k_edgetrans<<<g1, blk, 0, stream>>>(x, etW1, etb1, etW2, etb2, tws);

    dim3 ge(EE / 256, 2);    // 800000/256 = 3125 exactly
    k_hist<<<ge, blk, 0, stream>>>(ei, deg);

    dim3 gs(SCAN_BLK, 2);
    k_scan_local<<<gs, blk, 0, stream>>>(deg, rowptr, bsum);
    k_scan_bsum <<<dim3(1), dim3(64), 0, stream>>>(bsum, boff);
    k_scan_add  <<<gs, blk, 0, stream>>>(rowptr, cursor, boff);

    k_place<<<ge, blk, 0, stream>>>(ei, ea, bwW1, bwb1, bwW2, bwb2, bwW3, bwb3,
                                    bws, cursor, esrc, ecoef);
    k_gather<<<dim3(NN / 4, 2), blk, 0, stream>>>(rowptr, deg, esrc, ecoef, tws, agg);

    k_final<<<g1, blk, 0, stream>>>(agg, x, nuW, nub, lng, lnb, (float*)d_out);
}